// Round 4
// baseline (393.866 us; speedup 1.0000x reference)
//
#include <hip/hip_runtime.h>
#include <hip/hip_bf16.h>

// Net_40089224741482 round 4 (= round 3 + double-bias fix):
//  - all GEMMs (incl. expert heads) through one m97-style f16 MFMA kernel:
//    global_load_lds width=16, BK=64, LDS in MFMA-fragment order (conflict-free)
//  - expert epilogue split: z=[B,N*A] f16 (INCLUDES bexp bias) to HBM, then
//    fused tanh+distance+softmax+dot final kernel. bexp added exactly once.

typedef _Float16 half8 __attribute__((ext_vector_type(8)));
typedef float floatx16 __attribute__((ext_vector_type(16)));

namespace {
constexpr int kB = 4096, kS = 128, kA = 32, kH = 1024, kN = 256;
constexpr size_t al(size_t x) { return (x + 255) & ~size_t(255); }
// layout: FLAG | S16 | WEXPT | BUF2 | VAL | [weights+BUF1 region, aliased by Z]
constexpr size_t OFF_FLAG  = 0;
constexpr size_t OFF_S16   = 256;
constexpr size_t OFF_WEXPT = OFF_S16   + al((size_t)kB * kS * 2);
constexpr size_t OFF_BUF2  = OFF_WEXPT + al((size_t)kN * kA * kH * 2);
constexpr size_t OFF_VAL   = OFF_BUF2  + al((size_t)kB * kH * 2);
constexpr size_t OFF_WV1T  = OFF_VAL   + al((size_t)kB * kN * 4);
constexpr size_t OFF_WV2T  = OFF_WV1T  + al((size_t)kS * kH * 2);
constexpr size_t OFF_WV3T  = OFF_WV2T  + al((size_t)kH * kH * 2);
constexpr size_t OFF_WV4T  = OFF_WV3T  + al((size_t)kH * kH * 2);
constexpr size_t OFF_WL1T  = OFF_WV4T  + al((size_t)kH * kN * 2);
constexpr size_t OFF_BUF1  = OFF_WL1T  + al((size_t)kS * kH * 2);
constexpr size_t OFF_Z     = OFF_WV1T;  // aliases weights+BUF1 (all dead before Z written)
} // namespace

__device__ __forceinline__ float ldraw(const void* p, size_t i, int bf) {
    if (bf) return __uint_as_float(((unsigned)((const unsigned short*)p)[i]) << 16);
    return ((const float*)p)[i];
}

__device__ __forceinline__ void gl_lds16(const void* g, void* l) {
    __builtin_amdgcn_global_load_lds(
        (const __attribute__((address_space(1))) unsigned int*)g,
        (__attribute__((address_space(3))) unsigned int*)l, 16, 0, 0);
}

__device__ __forceinline__ float fast_tanh(float x) {
    x = fminf(9.f, fmaxf(-9.f, x));
    float e = __expf(2.f * x);
    return (e - 1.f) * __builtin_amdgcn_rcpf(e + 1.f);
}

// --- dtype detection: low 16 bits of fp32 N(0,1) are uniform mantissa bits;
// for packed bf16 they are a bf16 value whose exponent field sits near 127.
__global__ void detect_kernel(const unsigned int* __restrict__ s_raw, int* __restrict__ flag) {
    if (threadIdx.x == 0) {
        int c = 0;
        for (int i = 0; i < 256; ++i) {
            unsigned e = (s_raw[i] >> 7) & 0xFFu;
            if (e >= 118u && e <= 135u) c++;
        }
        *flag = (c > 128) ? 1 : 0;
    }
}

__global__ void convert_to_f16(const void* __restrict__ src, _Float16* __restrict__ dst,
                               int n, const int* __restrict__ flag) {
    const int bf = *flag;
    int i = blockIdx.x * blockDim.x + threadIdx.x;
    const int stride = gridDim.x * blockDim.x;
    for (; i < n; i += stride) dst[i] = (_Float16)ldraw(src, i, bf);
}

// src [Z][K][N] (fp32 or bf16) -> dst [Z][N][K] f16, 32x32 LDS-tiled
__global__ void transpose_to_f16(const void* __restrict__ src, _Float16* __restrict__ dst,
                                 int K, int N, const int* __restrict__ flag) {
    __shared__ float tile[32][33];
    const int bf = *flag;
    const size_t zo = (size_t)blockIdx.z * K * N;
    const int n0 = blockIdx.x * 32, k0 = blockIdx.y * 32;
    const int tx = threadIdx.x, ty = threadIdx.y;
#pragma unroll
    for (int j = 0; j < 32; j += 8)
        tile[ty + j][tx] = ldraw(src, zo + (size_t)(k0 + ty + j) * N + n0 + tx, bf);
    __syncthreads();
#pragma unroll
    for (int j = 0; j < 32; j += 8)
        dst[zo + (size_t)(n0 + ty + j) * K + k0 + tx] = (_Float16)tile[tx][ty + j];
}

// --- f16 MFMA GEMM: C[M,N] = act(A[M,K] @ Bt[N,K]^T + bias)
// 256 thr = 4 waves (2x2), tile 128x128, wave 64x64 = 2x2 mfma_32x32x16.
// BK=64; staging via global_load_lds(16B); LDS in MFMA fragment order:
//   chunk(ks, blk, lane) holds X[x0 + blk*32 + (lane&31)][k0 + ks*16 + (lane>>5)*8 ..+7]
// so every ds_read_b128 is base + lane*16 (dense, conflict-free).
template <int DO_RELU, int OUT_F16>
__launch_bounds__(256)
__global__ void mfma_gemm(const _Float16* __restrict__ A, const _Float16* __restrict__ Bt,
                          const void* __restrict__ bias_raw, void* __restrict__ Cout,
                          const int* __restrict__ flagp, int N, int K) {
    __shared__ _Float16 As[8192];  // 4 ks * 4 blk * 64 lanes * 8 f16
    __shared__ _Float16 Bs[8192];
    const int tid = threadIdx.x;
    const int lane = tid & 63;
    const int w = tid >> 6, wr = w >> 1, wc = w & 1;
    const int m0 = blockIdx.y * 128, n0 = blockIdx.x * 128;

    // staging source: wave w covers rows blk=w, 16B chunk (lane>>5) of k-quarter t
    const _Float16* gA = A + (size_t)(m0 + w * 32 + (lane & 31)) * K + (lane >> 5) * 8;
    const _Float16* gB = Bt + (size_t)(n0 + w * 32 + (lane & 31)) * K + (lane >> 5) * 8;
    _Float16* lA = As + (size_t)(w * 64 + lane) * 8;
    _Float16* lB = Bs + (size_t)(w * 64 + lane) * 8;

    // fragment read bases (f16 offsets): + ks*2048 + mi*512
    const _Float16* pA = As + (size_t)(wr * 2 * 64 + lane) * 8;
    const _Float16* pB = Bs + (size_t)(wc * 2 * 64 + lane) * 8;

    floatx16 zero;
#pragma unroll
    for (int i = 0; i < 16; ++i) zero[i] = 0.f;
    floatx16 acc[2][2] = {zero, zero, zero, zero};

    for (int k0 = 0; k0 < K; k0 += 64) {
#pragma unroll
        for (int t = 0; t < 4; ++t) {
            gl_lds16(gA + k0 + t * 16, lA + t * 2048);
            gl_lds16(gB + k0 + t * 16, lB + t * 2048);
        }
        __syncthreads();
#pragma unroll
        for (int ks = 0; ks < 4; ++ks) {
            half8 af0 = *(const half8*)(pA + ks * 2048);
            half8 af1 = *(const half8*)(pA + ks * 2048 + 512);
            half8 bf0 = *(const half8*)(pB + ks * 2048);
            half8 bf1 = *(const half8*)(pB + ks * 2048 + 512);
            acc[0][0] = __builtin_amdgcn_mfma_f32_32x32x16_f16(af0, bf0, acc[0][0], 0, 0, 0);
            acc[0][1] = __builtin_amdgcn_mfma_f32_32x32x16_f16(af0, bf1, acc[0][1], 0, 0, 0);
            acc[1][0] = __builtin_amdgcn_mfma_f32_32x32x16_f16(af1, bf0, acc[1][0], 0, 0, 0);
            acc[1][1] = __builtin_amdgcn_mfma_f32_32x32x16_f16(af1, bf1, acc[1][1], 0, 0, 0);
        }
        __syncthreads();
    }

    const int bf = *flagp;
    const int am = lane & 31;
    const int half = lane >> 5;
#pragma unroll
    for (int mi = 0; mi < 2; ++mi)
#pragma unroll
        for (int ni = 0; ni < 2; ++ni) {
            const int Rb = m0 + wr * 64 + mi * 32;
            const int Cb = n0 + wc * 64 + ni * 32 + am;
            const float bv = ldraw(bias_raw, Cb, bf);
#pragma unroll
            for (int rr = 0; rr < 16; ++rr) {
                const int row = Rb + (rr & 3) + 8 * (rr >> 2) + 4 * half;
                float x = acc[mi][ni][rr] + bv;
                if (DO_RELU) x = fmaxf(x, 0.f);
                if (OUT_F16) ((_Float16*)Cout)[(size_t)row * N + Cb] = (_Float16)x;
                else ((float*)Cout)[(size_t)row * N + Cb] = x;
            }
        }
}

// --- fused: tanh(z) -> ||c-a|| -> softmax(-dist) . values, one block per b
// NOTE: z already includes the bexp bias (added in the expert GEMM epilogue).
__launch_bounds__(256)
__global__ void final_fused(const _Float16* __restrict__ z, const void* __restrict__ a_raw,
                            const float* __restrict__ values, const int* __restrict__ flag,
                            void* __restrict__ out) {
    const int b = blockIdx.x;
    const int n = threadIdx.x;
    const int bf = *flag;
    __shared__ float as_[32];
    if (n < 32) as_[n] = ldraw(a_raw, (size_t)b * kA + n, bf);
    __syncthreads();

    const _Float16* zp = z + (size_t)b * (kN * kA) + n * kA;
    float zl[32];
#pragma unroll
    for (int t = 0; t < 4; ++t) {
        half8 h = *(const half8*)(zp + t * 8);
#pragma unroll
        for (int j = 0; j < 8; ++j) zl[t * 8 + j] = (float)h[j];
    }
    float sum = 0.f;
#pragma unroll
    for (int a = 0; a < 32; ++a) {
        const float c = fast_tanh(zl[a]);  // MAX_A=1; bexp already in z
        const float d = c - as_[a];
        sum = fmaf(d, d, sum);
    }
    const float dist = sqrtf(sum + 0.01f);
    const float v = values[(size_t)b * kN + n];

    const int wid = n >> 6, lane = n & 63;
    __shared__ float red[8];
    __shared__ float rw[4], rwv[4];
    float m = dist;
    for (int off = 32; off > 0; off >>= 1) m = fminf(m, __shfl_down(m, off));
    if (lane == 0) red[wid] = m;
    __syncthreads();
    if (n == 0) red[4] = fminf(fminf(red[0], red[1]), fminf(red[2], red[3]));
    __syncthreads();
    const float dmin = red[4];

    float wgt = expf(dmin - dist);
    float wv = wgt * v;
    for (int off = 32; off > 0; off >>= 1) {
        wgt += __shfl_down(wgt, off);
        wv += __shfl_down(wv, off);
    }
    if (lane == 0) { rw[wid] = wgt; rwv[wid] = wv; }
    __syncthreads();
    if (n == 0) {
        const float sw = rw[0] + rw[1] + rw[2] + rw[3];
        const float swv = rwv[0] + rwv[1] + rwv[2] + rwv[3];
        const float o = swv / sw;
        if (bf) ((__hip_bfloat16*)out)[b] = __float2bfloat16(o);
        else    ((float*)out)[b] = o;
    }
}

extern "C" void kernel_launch(void* const* d_in, const int* in_sizes, int n_in,
                              void* d_out, int out_size, void* d_ws, size_t ws_size,
                              hipStream_t stream) {
    (void)in_sizes; (void)n_in; (void)out_size; (void)ws_size;
    char* ws = (char*)d_ws;
    int* flag = (int*)(ws + OFF_FLAG);
    _Float16* s16   = (_Float16*)(ws + OFF_S16);
    _Float16* wv1t  = (_Float16*)(ws + OFF_WV1T);
    _Float16* wv2t  = (_Float16*)(ws + OFF_WV2T);
    _Float16* wv3t  = (_Float16*)(ws + OFF_WV3T);
    _Float16* wv4t  = (_Float16*)(ws + OFF_WV4T);
    _Float16* wl1t  = (_Float16*)(ws + OFF_WL1T);
    _Float16* wexpt = (_Float16*)(ws + OFF_WEXPT);
    _Float16* buf1  = (_Float16*)(ws + OFF_BUF1);
    _Float16* buf2  = (_Float16*)(ws + OFF_BUF2);
    float* values   = (float*)(ws + OFF_VAL);
    _Float16* z     = (_Float16*)(ws + OFF_Z);

    detect_kernel<<<1, 64, 0, stream>>>((const unsigned int*)d_in[0], flag);
    convert_to_f16<<<512, 256, 0, stream>>>(d_in[0], s16, kB * kS, flag);

    dim3 tb(32, 8);
    transpose_to_f16<<<dim3(kH / 32, kS / 32, 1), tb, 0, stream>>>(d_in[2],  wv1t,  kS, kH, flag);
    transpose_to_f16<<<dim3(kH / 32, kH / 32, 1), tb, 0, stream>>>(d_in[4],  wv2t,  kH, kH, flag);
    transpose_to_f16<<<dim3(kH / 32, kH / 32, 1), tb, 0, stream>>>(d_in[6],  wv3t,  kH, kH, flag);
    transpose_to_f16<<<dim3(kN / 32, kH / 32, 1), tb, 0, stream>>>(d_in[8],  wv4t,  kH, kN, flag);
    transpose_to_f16<<<dim3(kH / 32, kS / 32, 1), tb, 0, stream>>>(d_in[10], wl1t,  kS, kH, flag);
    transpose_to_f16<<<dim3(kA / 32, kH / 32, kN), tb, 0, stream>>>(d_in[12], wexpt, kH, kA, flag);

    // value MLP
    mfma_gemm<1, 1><<<dim3(kH / 128, kB / 128), 256, 0, stream>>>(s16,  wv1t, d_in[3], buf1, flag, kH, kS);
    mfma_gemm<1, 1><<<dim3(kH / 128, kB / 128), 256, 0, stream>>>(buf1, wv2t, d_in[5], buf2, flag, kH, kH);
    mfma_gemm<1, 1><<<dim3(kH / 128, kB / 128), 256, 0, stream>>>(buf2, wv3t, d_in[7], buf1, flag, kH, kH);
    mfma_gemm<0, 0><<<dim3(kN / 128, kB / 128), 256, 0, stream>>>(buf1, wv4t, d_in[9], values, flag, kN, kH);
    // location hidden
    mfma_gemm<1, 1><<<dim3(kH / 128, kB / 128), 256, 0, stream>>>(s16,  wl1t, d_in[11], buf2, flag, kH, kS);
    // expert heads as one big GEMM: z[B, N*A] = buf2 @ wexpt^T + bexp (bias added HERE, once)
    mfma_gemm<0, 1><<<dim3((kN * kA) / 128, kB / 128), 256, 0, stream>>>(buf2, wexpt, d_in[13], z, flag, kN * kA, kH);
    // fused tanh + distance + softmax + value readout
    final_fused<<<kB, 256, 0, stream>>>(z, d_in[1], values, flag, d_out);
}